// Round 8
// baseline (5345558.984 us; speedup 1.0000x reference)
//
#include <hip/hip_runtime.h>

// ---------------- constants ----------------
#define H_    1024      // hidden = n_nodes
#define T_    128       // GRU input size
#define B_    32        // batch
#define S_    1024      // sequence length (node axis)
#define NW_   32        // team size: 32 blocks on ONE XCD
#define JB_   32        // gate-cols per block
#define NN_   (1024*1024)
#define ROWP  1162      // padded LDS row stride in elems (581 dwords == 5 mod 32)

typedef float f32x4 __attribute__((ext_vector_type(4)));
typedef __bf16 bf16x8 __attribute__((ext_vector_type(8)));

union FragU { uint4 q; bf16x8 v; unsigned short u[8]; };

static __device__ __forceinline__ unsigned short f2bf(float x) {
  unsigned u = __float_as_uint(x);
  u = (u + 0x7FFFu + ((u >> 16) & 1u)) >> 16;
  return (unsigned short)u;
}
static __device__ __forceinline__ float sigm(float x) { return 1.f / (1.f + __expf(-x)); }
static __device__ __forceinline__ float tanh_(float x) {
  float a = fabsf(x);
  float e = __expf(2.f * a);
  float t = 1.f - 2.f / (e + 1.f);
  return copysignf(t, x);
}
static __device__ __forceinline__ float lrelu(float x) { return x > 0.f ? x : 0.2f * x; }

// sc0 loads: bypass L1, read the XCD's shared L2 (intra-XCD coherence point)
static __device__ __forceinline__ int ld_flag_sc0(const int* p) {
  int v;
  asm volatile("global_load_dword %0, %1, off sc0\n\ts_waitcnt vmcnt(0)"
               : "=v"(v) : "v"(p) : "memory");
  return v;
}
static __device__ __forceinline__ void ld8_sc0(const void* base,
    uint4& r0, uint4& r1, uint4& r2, uint4& r3,
    uint4& r4, uint4& r5, uint4& r6, uint4& r7) {
  asm volatile(
    "global_load_dwordx4 %0, %8, off sc0\n\t"
    "global_load_dwordx4 %1, %8, off offset:16 sc0\n\t"
    "global_load_dwordx4 %2, %8, off offset:32 sc0\n\t"
    "global_load_dwordx4 %3, %8, off offset:48 sc0\n\t"
    "global_load_dwordx4 %4, %8, off offset:64 sc0\n\t"
    "global_load_dwordx4 %5, %8, off offset:80 sc0\n\t"
    "global_load_dwordx4 %6, %8, off offset:96 sc0\n\t"
    "global_load_dwordx4 %7, %8, off offset:112 sc0\n\t"
    "s_waitcnt vmcnt(0)"
    : "=&v"(r0), "=&v"(r1), "=&v"(r2), "=&v"(r3),
      "=&v"(r4), "=&v"(r5), "=&v"(r6), "=&v"(r7)
    : "v"(base) : "memory");
}
static __device__ __forceinline__ void st_u32(unsigned int* p, unsigned int v) {
  asm volatile("global_store_dword %0, %1, off" :: "v"(p), "v"(v) : "memory");
}

// ---------------- x transpose: [B,T,N] f32 -> xT [N][B][T] bf16 ----------------
__global__ __launch_bounds__(256) void k_transpose(const float* __restrict__ x,
                                                   unsigned short* __restrict__ xT) {
  __shared__ float tile[128][65];
  int b  = blockIdx.x >> 4;
  int n0 = (blockIdx.x & 15) * 64;
  int tid = threadIdx.x;
  int sub = tid >> 6, nn = tid & 63;
  for (int it = 0; it < 32; ++it) {
    int t = it * 4 + sub;
    tile[t][nn] = x[(size_t)(b * 128 + t) * 1024 + n0 + nn];
  }
  __syncthreads();
  int nl = tid >> 7, tt = tid & 127;
  for (int it = 0; it < 32; ++it) {
    int n = it * 2 + nl;
    xT[(size_t)(n0 + n) * 4096 + b * 128 + tt] = f2bf(tile[tt][n]);
  }
}

// ---------------- persistent GRU: 32-block team on ONE XCD ----------------
// Launch 512 blocks; team formed via HW_REG_XCC_ID ticketing; losers exit.
// Exchange through the XCD's L2: plain stores + sc0 loads + narrow flag poll.
__global__ __launch_bounds__(512, 2) void k_gru(
    const float* __restrict__ w_ih, const float* __restrict__ w_hh,
    const float* __restrict__ b_ih, const float* __restrict__ b_hh,
    const float* __restrict__ wkey, const float* __restrict__ wqry,
    const unsigned short* __restrict__ xT,
    unsigned short* __restrict__ hg,      // [2][B_][H_] bf16 (row-major)
    int* __restrict__ flags,              // [NW_]
    int* __restrict__ team,               // [0..15] tickets, [16] winner
    float* __restrict__ key_v, float* __restrict__ qry_v)
{
  __shared__ unsigned short h_sm[32 * ROWP];  // [b][1152+pad]: h cols 0..1023, x cols 1024..1151
  __shared__ float gh[2][B_][132];            // [khalf][b][r z nh nx]
  __shared__ float wk_lds[S_], wq_lds[S_];
  __shared__ int s_rank;

  const int tid  = threadIdx.x;
  const int lane = tid & 63;
  const int wave = tid >> 6;

  // ---- team formation: first XCD to collect 32 tickets wins ----
  if (tid == 0) {
    unsigned xcd = (unsigned)__builtin_amdgcn_s_getreg(63508) & 0xFu; // HW_REG_XCC_ID (id20,off0,w32)
    int t = __hip_atomic_fetch_add(&team[xcd], 1, __ATOMIC_RELAXED, __HIP_MEMORY_SCOPE_AGENT);
    int rk = -1;
    if (t < NW_) {
      if (t == NW_ - 1) {
        int exp = -1;
        __hip_atomic_compare_exchange_strong(&team[16], &exp, (int)xcd,
            __ATOMIC_RELAXED, __ATOMIC_RELAXED, __HIP_MEMORY_SCOPE_AGENT);
      }
      int w = -1; long bud = 200000000;
      do { w = __hip_atomic_load(&team[16], __ATOMIC_RELAXED, __HIP_MEMORY_SCOPE_AGENT); }
      while (w < 0 && --bud > 0);
      if (w == (int)xcd) rk = t;
    }
    s_rank = rk;
  }
  __syncthreads();
  const int rank = s_rank;
  if (rank < 0) return;
  const int j0 = rank * JB_;

  for (int i = tid; i < S_; i += 512) { wk_lds[i] = wkey[i]; wq_lds[i] = wqry[i]; }

  // ---- weight fragments: 8 waves x (full pair P + half pair Q), 24 jobs balanced ----
  // pair pi(0..11) = (ntile = pi%6, khalf = pi/6); P: pi=wave; Q: pi=8+(wave>>1), mtile=wave&1
  const int ntP = (wave < 6) ? wave : (wave - 6);
  const int khP = (wave < 6) ? 0 : 1;
  const int ntQ = 2 + (wave >> 1);
  const int mQ  = wave & 1;

  bf16x8 wP[18], wQ[18];
  {
    const int col = lane & 15, kg = (lane >> 4) & 3;
    const int growP = (ntP >> 1) * H_ + j0 + (ntP & 1) * 16 + col;
    const int growQ = (ntQ >> 1) * H_ + j0 + (ntQ & 1) * 16 + col;
    for (int ksl = 0; ksl < 18; ++ksl) {
      { int k = (khP * 18 + ksl) * 32 + kg * 8;
        const float* p = (k < H_) ? (w_hh + (size_t)growP * H_ + k)
                                  : (w_ih + (size_t)growP * T_ + (k - H_));
        FragU cv;
        #pragma unroll
        for (int e = 0; e < 8; ++e) cv.u[e] = f2bf(p[e]);
        wP[ksl] = cv.v; }
      { int k = (18 + ksl) * 32 + kg * 8;   // Q is always khalf 1
        const float* p = (k < H_) ? (w_hh + (size_t)growQ * H_ + k)
                                  : (w_ih + (size_t)growQ * T_ + (k - H_));
        FragU cv;
        #pragma unroll
        for (int e = 0; e < 8; ++e) cv.u[e] = f2bf(p[e]);
        wQ[ksl] = cv.v; }
    }
  }

  // epilogue mapping: thread -> (batch eb, col pair jp): 2 h elems per thread
  const int jp  = tid & 15;
  const int eb  = tid >> 4;
  const int jl0 = jp * 2, jl1 = jp * 2 + 1;
  const float bs_r0 = b_ih[j0 + jl0] + b_hh[j0 + jl0];
  const float bs_r1 = b_ih[j0 + jl1] + b_hh[j0 + jl1];
  const float bs_z0 = b_ih[H_ + j0 + jl0] + b_hh[H_ + j0 + jl0];
  const float bs_z1 = b_ih[H_ + j0 + jl1] + b_hh[H_ + j0 + jl1];
  const float bn_i0 = b_ih[2 * H_ + j0 + jl0], bn_i1 = b_ih[2 * H_ + j0 + jl1];
  const float bn_h0 = b_hh[2 * H_ + j0 + jl0], bn_h1 = b_hh[2 * H_ + j0 + jl1];

  float h0 = 0.f, h1 = 0.f;
  float kacc0 = 0.f, kacc1 = 0.f, qacc0 = 0.f, qacc1 = 0.f;
  long spin_budget = 50000000;

  // staging mapping: thread -> (row bb, 128B chunk ub)
  const int bb = tid & 31;
  const int ub = tid >> 5;   // 0..15

  for (int s = 0; s < S_; ++s) {
    // x chunk for this step (L2-cached plain load; before poll)
    const uint4 xv = *(const uint4*)(xT + (size_t)s * 4096 + bb * 128 + ub * 8);

    // ---- narrow flag poll (wave 0 only, 1 sc0 dword per lane) ----
    if (wave == 0) {
      const int* fp = flags + (lane & 31);
      while (true) {
        int v = ld_flag_sc0(fp);
        if (__all(v >= s)) break;
        if (--spin_budget < 0) break;
        __builtin_amdgcn_s_sleep(1);
      }
    }
    __syncthreads();   // bar0: all flags >= s certified

    // ---- stage h^(s-1): 64KB via sc0 dwordx4 batch -> LDS ----
    {
      const unsigned short* hp = hg + ((s + 1) & 1) * (B_ * H_) + bb * H_ + ub * 64;
      uint4 r0, r1, r2, r3, r4, r5, r6, r7;
      ld8_sc0(hp, r0, r1, r2, r3, r4, r5, r6, r7);
      unsigned short* dst = &h_sm[bb * ROWP + ub * 64];
      *(uint4*)(dst +  0) = r0;  *(uint4*)(dst +  8) = r1;
      *(uint4*)(dst + 16) = r2;  *(uint4*)(dst + 24) = r3;
      *(uint4*)(dst + 32) = r4;  *(uint4*)(dst + 40) = r5;
      *(uint4*)(dst + 48) = r6;  *(uint4*)(dst + 56) = r7;
      *(uint4*)&h_sm[bb * ROWP + 1024 + ub * 8] = xv;
    }
    __syncthreads();   // bar1: h_sm ready

    // ---- MFMA: 3 jobs/wave (P x m0, P x m1, Q x mQ), K-half split ----
    {
      const int lr = lane & 15, kg = lane >> 4;
      const int khPo = khP * 18;
      f32x4 aA = {0.f,0.f,0.f,0.f}, aB = {0.f,0.f,0.f,0.f};
      f32x4 aC = {0.f,0.f,0.f,0.f}, aCx = {0.f,0.f,0.f,0.f};
      #pragma unroll
      for (int ksl = 0; ksl < 18; ++ksl) {
        FragU fA, fB, fC;
        fA.q = *(const uint4*)&h_sm[lr * ROWP        + (khPo + ksl) * 32 + kg * 8];
        fB.q = *(const uint4*)&h_sm[(16 + lr) * ROWP + (khPo + ksl) * 32 + kg * 8];
        aA = __builtin_amdgcn_mfma_f32_16x16x32_bf16(fA.v, wP[ksl], aA, 0, 0, 0);
        aB = __builtin_amdgcn_mfma_f32_16x16x32_bf16(fB.v, wP[ksl], aB, 0, 0, 0);
        fC.q = *(const uint4*)&h_sm[(mQ * 16 + lr) * ROWP + (18 + ksl) * 32 + kg * 8];
        if (ntQ >= 4 && ksl >= 14)
          aCx = __builtin_amdgcn_mfma_f32_16x16x32_bf16(fC.v, wQ[ksl], aCx, 0, 0, 0);
        else
          aC  = __builtin_amdgcn_mfma_f32_16x16x32_bf16(fC.v, wQ[ksl], aC, 0, 0, 0);
      }
      const int colbP = (ntP >> 1) * 32 + (ntP & 1) * 16 + lr;
      const int colbQ = (ntQ >> 1) * 32 + (ntQ & 1) * 16 + lr;
      const int rb = (lane >> 4) * 4;
      #pragma unroll
      for (int r = 0; r < 4; ++r) {
        gh[khP][rb + r][colbP]      = aA[r];
        gh[khP][16 + rb + r][colbP] = aB[r];
        gh[1][mQ * 16 + rb + r][colbQ] = aC[r];
        if (ntQ >= 4) gh[1][mQ * 16 + rb + r][96 + (ntQ & 1) * 16 + lr] = aCx[r];
      }
    }
    __syncthreads();   // bar2: gh ready

    // ---- gate epilogue: 2 (b,j) per thread ----
    {
      float rs0 = gh[0][eb][jl0]      + gh[1][eb][jl0]      + bs_r0;
      float rs1 = gh[0][eb][jl1]      + gh[1][eb][jl1]      + bs_r1;
      float zs0 = gh[0][eb][32 + jl0] + gh[1][eb][32 + jl0] + bs_z0;
      float zs1 = gh[0][eb][32 + jl1] + gh[1][eb][32 + jl1] + bs_z1;
      float nh0 = gh[0][eb][64 + jl0] + gh[1][eb][64 + jl0] + bn_h0;
      float nh1 = gh[0][eb][64 + jl1] + gh[1][eb][64 + jl1] + bn_h1;
      float nx0 = gh[1][eb][96 + jl0] + bn_i0;
      float nx1 = gh[1][eb][96 + jl1] + bn_i1;
      float r0 = sigm(rs0), r1 = sigm(rs1);
      float z0 = sigm(zs0), z1 = sigm(zs1);
      float n0 = tanh_(nx0 + r0 * nh0), n1 = tanh_(nx1 + r1 * nh1);
      h0 = (1.f - z0) * n0 + z0 * h0;
      h1 = (1.f - z1) * n1 + z1 * h1;
      kacc0 += wk_lds[s] * h0;  kacc1 += wk_lds[s] * h1;
      qacc0 += wq_lds[s] * h0;  qacc1 += wq_lds[s] * h1;
      unsigned int word = (unsigned)f2bf(h0) | ((unsigned)f2bf(h1) << 16);
      *(unsigned int*)(hg + (s & 1) * (B_ * H_) + eb * H_ + j0 + jl0) = word;
    }
    asm volatile("s_waitcnt vmcnt(0)" ::: "memory");  // h stores in L2
    __syncthreads();   // bar3: all waves' stores done
    if (tid == 0) st_u32((unsigned int*)&flags[rank], (unsigned)(s + 1));
  }

  key_v[eb * H_ + j0 + jl0] = kacc0;
  key_v[eb * H_ + j0 + jl1] = kacc1;
  qry_v[eb * H_ + j0 + jl0] = qacc0;
  qry_v[eb * H_ + j0 + jl1] = qacc1;
}

// ---------------- qmax over j per batch ----------------
__global__ __launch_bounds__(256) void k_qmax(const float* __restrict__ qry_v,
                                              float* __restrict__ qmax) {
  int b = blockIdx.x, tid = threadIdx.x;
  float m = -1e30f;
  for (int i = tid; i < 1024; i += 256) m = fmaxf(m, qry_v[b * 1024 + i]);
  #pragma unroll
  for (int off = 32; off; off >>= 1) m = fmaxf(m, __shfl_xor(m, off));
  __shared__ float red[4];
  if ((tid & 63) == 0) red[tid >> 6] = m;
  __syncthreads();
  if (tid == 0) qmax[b] = fmaxf(fmaxf(red[0], red[1]), fmaxf(red[2], red[3]));
}

// ---------------- softmax denominators: one wave per (b,i) row ----------------
__global__ __launch_bounds__(256) void k_denom(const float* __restrict__ key_v,
                                               const float* __restrict__ qry_v,
                                               const float* __restrict__ qmax,
                                               float* __restrict__ mrow,
                                               float* __restrict__ rden) {
  int tid = threadIdx.x, lane = tid & 63;
  int row = blockIdx.x * 4 + (tid >> 6);           // b*1024+i
  int b = row >> 10;
  float k  = key_v[row];
  float mx = lrelu(k + qmax[b]);
  float sum = 0.f;
  for (int j = lane; j < 1024; j += 64)
    sum += __expf(lrelu(k + qry_v[b * 1024 + j]) - mx);
  #pragma unroll
  for (int off = 32; off; off >>= 1) sum += __shfl_xor(sum, off);
  if (lane == 0) { mrow[row] = mx; rden[row] = 1.f / sum; }
}

// ---------------- A_mean + degree ----------------
__global__ __launch_bounds__(256) void k_amean(const float* __restrict__ key_v,
                                               const float* __restrict__ qry_v,
                                               const float* __restrict__ mrow,
                                               const float* __restrict__ rden,
                                               float* __restrict__ A,
                                               float* __restrict__ degree) {
  __shared__ float qs[32][33];
  __shared__ float ks[32][9], ms[32][9], rs[32][9];
  int tid = threadIdx.x;
  int it = blockIdx.x >> 5, jt = blockIdx.x & 31;
  int i0 = it * 8, j0 = jt * 32;
  #pragma unroll
  for (int c = 0; c < 4; ++c) {
    int idx = tid + c * 256;
    int b = idx >> 5, j = idx & 31;
    qs[b][j] = qry_v[b * 1024 + j0 + j];
  }
  { int b = tid >> 3, ii = tid & 7;
    ks[b][ii] = key_v[b * 1024 + i0 + ii];
    ms[b][ii] = mrow[b * 1024 + i0 + ii];
    rs[b][ii] = rden[b * 1024 + i0 + ii]; }
  __syncthreads();
  int il = tid >> 5, jl = tid & 31;
  float acc = 0.f;
  #pragma unroll 4
  for (int b = 0; b < 32; ++b)
    acc += __expf(lrelu(ks[b][il] + qs[b][jl]) - ms[b][il]) * rs[b][il];
  acc *= (1.f / 32.f);
  A[(size_t)(i0 + il) * 1024 + j0 + jl] = acc;
  float v = acc;
  #pragma unroll
  for (int off = 16; off; off >>= 1) v += __shfl_xor(v, off);
  if (jl == 0) atomicAdd(&degree[i0 + il], v);
}

// ---------------- symmetrize + laplacian + attention output ----------------
__global__ __launch_bounds__(256) void k_lap(const float* __restrict__ A,
                                             const float* __restrict__ degree,
                                             float* __restrict__ lap,
                                             float* __restrict__ att) {
  __shared__ float ta[32][33], tb[32][33];
  int it = blockIdx.x >> 5, jt = blockIdx.x & 31;
  int i0 = it * 32, j0 = jt * 32;
  int tid = threadIdx.x;
  int r = tid >> 5, c = tid & 31;
  for (int rr = r; rr < 32; rr += 8) {
    ta[rr][c] = A[(size_t)(i0 + rr) * 1024 + j0 + c];
    tb[rr][c] = A[(size_t)(j0 + rr) * 1024 + i0 + c];
  }
  __syncthreads();
  for (int rr = r; rr < 32; rr += 8) {
    int i = i0 + rr, j = j0 + c;
    float asym = 0.5f * (ta[rr][c] + tb[c][rr]);
    float di = 1.f / (sqrtf(degree[i]) + 1e-7f);
    float dj = 1.f / (sqrtf(degree[j]) + 1e-7f);
    float lv = di * dj * (((i == j) ? degree[i] : 0.f) - asym);
    att[(size_t)i * 1024 + j] = asym;
    lap[(size_t)i * 1024 + j] = lv;
  }
}

// ---------------- fp32 tiled GEMM: C = alpha*A@B - sub ----------------
__global__ __launch_bounds__(256) void k_gemm(const float* __restrict__ A,
                                              const float* __restrict__ B,
                                              float* __restrict__ C, float alpha,
                                              const float* __restrict__ sub) {
  __shared__ float As[16][68], Bs[16][68];
  int it = blockIdx.x >> 4, jt = blockIdx.x & 15;
  int i0 = it * 64, j0 = jt * 64;
  int tid = threadIdx.x;
  float acc[4][4] = {};
  int rb = (tid >> 4) * 4, cb = (tid & 15) * 4;
  int arow = tid >> 2, akk = (tid & 3) * 4;
  int brow = tid >> 4, bjc = (tid & 15) * 4;
  for (int kt = 0; kt < 64; ++kt) {
    float4 av = *(const float4*)&A[(size_t)(i0 + arow) * 1024 + kt * 16 + akk];
    float4 bv = *(const float4*)&B[(size_t)(kt * 16 + brow) * 1024 + j0 + bjc];
    As[akk + 0][arow] = av.x; As[akk + 1][arow] = av.y;
    As[akk + 2][arow] = av.z; As[akk + 3][arow] = av.w;
    *(float4*)&Bs[brow][bjc] = bv;
    __syncthreads();
    #pragma unroll
    for (int k = 0; k < 16; ++k) {
      float4 a4 = *(const float4*)&As[k][rb];
      float4 b4 = *(const float4*)&Bs[k][cb];
      float aa[4] = {a4.x, a4.y, a4.z, a4.w};
      float bb[4] = {b4.x, b4.y, b4.z, b4.w};
      #pragma unroll
      for (int rr = 0; rr < 4; ++rr)
        #pragma unroll
        for (int cc = 0; cc < 4; ++cc) acc[rr][cc] += aa[rr] * bb[cc];
    }
    __syncthreads();
  }
  #pragma unroll
  for (int rr = 0; rr < 4; ++rr)
    #pragma unroll
    for (int cc = 0; cc < 4; ++cc) {
      size_t idx = (size_t)(i0 + rb + rr) * 1024 + j0 + cb + cc;
      float v = alpha * acc[rr][cc];
      if (sub) v -= sub[idx];
      C[idx] = v;
    }
}

// ---------------- launch ----------------
extern "C" void kernel_launch(void* const* d_in, const int* in_sizes, int n_in,
                              void* d_out, int out_size, void* d_ws, size_t ws_size,
                              hipStream_t stream) {
  const float* x    = (const float*)d_in[0];
  const float* w_ih = (const float*)d_in[1];
  const float* w_hh = (const float*)d_in[2];
  const float* b_ih = (const float*)d_in[3];
  const float* b_hh = (const float*)d_in[4];
  const float* wkey = (const float*)d_in[5];
  const float* wqry = (const float*)d_in[6];
  float* out = (float*)d_out;

  char* ws = (char*)d_ws;
  unsigned short* xT  = (unsigned short*)(ws);             // 8 MB
  unsigned short* hg  = (unsigned short*)(ws + 8388608);   // 128 KB (2 x 64KB)
  int*   flags        = (int*)  (ws + 8519680);            // 4 KB
  int*   team         = (int*)  (ws + 8523776);            // 4 KB: tickets[16], winner[16]
  float* key_v        = (float*)(ws + 8527872);            // 128 KB
  float* qry_v        = (float*)(ws + 8658944);            // 128 KB
  float* qmax         = (float*)(ws + 8790016);            // 4 KB
  float* mrow         = (float*)(ws + 8794112);            // 128 KB
  float* rden         = (float*)(ws + 8925184);            // 128 KB
  float* degree       = (float*)(ws + 9056256);            // 4 KB
  float* A            = (float*)(ws + 9060352);            // 4 MB

  (void)hipMemsetAsync(hg, 0, 131072 + 4096, stream);     // h0 = 0, flags = 0
  (void)hipMemsetAsync(team, 0, 64, stream);              // tickets = 0
  (void)hipMemsetAsync((char*)team + 64, 0xFF, 4, stream);// winner = -1
  (void)hipMemsetAsync(degree, 0, 4096, stream);
  (void)hipMemsetAsync(out, 0, (size_t)NN_ * 4, stream);  // L0 = zeros

  k_transpose<<<512, 256, 0, stream>>>(x, xT);
  k_gru<<<512, 512, 0, stream>>>(w_ih, w_hh, b_ih, b_hh, wkey, wqry, xT, hg, flags, team, key_v, qry_v);
  k_qmax<<<32, 256, 0, stream>>>(qry_v, qmax);
  k_denom<<<8192, 256, 0, stream>>>(key_v, qry_v, qmax, mrow, rden);
  k_amean<<<4096, 256, 0, stream>>>(key_v, qry_v, mrow, rden, A, degree);
  k_lap<<<1024, 256, 0, stream>>>(A, degree, out + NN_, out + (size_t)4 * NN_);
  k_gemm<<<256, 256, 0, stream>>>(out + NN_, out + NN_, out + (size_t)2 * NN_, 2.f, nullptr);
  k_gemm<<<256, 256, 0, stream>>>(out + NN_, out + (size_t)2 * NN_, out + (size_t)3 * NN_, 2.f, out + NN_);
}